// Round 1
// baseline (324.916 us; speedup 1.0000x reference)
//
#include <hip/hip_runtime.h>

// Problem constants
#define B_     64
#define CIN_   3
#define HW_    96
#define COUT_  96
#define KK_    75          // CIN*KH*KW
#define KP_    76          // padded K (multiple of 4 for float4 LDS reads)
#define HOUT_  48
#define L_     2304        // HOUT*WOUT
#define LR_    0.02f
#define DELTA_ -0.4f
#define NCHUNK 9           // l-chunks per batch (2304/256)
#define CHUNK  256
#define NPART  (B_*NCHUNK) // 576 partial rows
#define ROW    (COUT_*KK_ + COUT_)   // 7296 floats: 7200 yx + 96 yy
#define OUT_ELEMS (B_*COUT_*L_)      // 14155776 conv-out floats

// Kernel 1: conv forward + tot + top-2 + block-local yx/yy partials.
// grid (9, 64), block 256 (one thread per output position l).
__global__ __launch_bounds__(256) void k1_main(
    const float* __restrict__ x, const float* __restrict__ w,
    float* __restrict__ out, float* __restrict__ part)
{
  __shared__ __align__(16) float Ws[COUT_ * KP_];   // W
  __shared__ __align__(16) float Wps[COUT_ * KP_];  // W*|W|  (reused as yx accum)
  __shared__ float yyloc[COUT_];
  const int tid = threadIdx.x;

  // stage weights into LDS (pad k=75 with zero)
  for (int idx = tid; idx < COUT_ * KP_; idx += 256) {
    int o = idx / KP_, k = idx - o * KP_;
    float v = (k < KK_) ? w[o * KK_ + k] : 0.0f;
    Ws[idx]  = v;
    Wps[idx] = v * fabsf(v);   // sign(w)*|w|^(p-1), p=3
  }
  __syncthreads();

  const int b  = blockIdx.y;
  const int l  = blockIdx.x * CHUNK + tid;
  const int oh = l / HOUT_;
  const int ow = l - oh * HOUT_;
  const float* xb = x + (size_t)b * (CIN_ * HW_ * HW_);

  // im2col gather: pre[k], k = c*25 + i*5 + j (channel-major, matches Unfold)
  float pre[KP_];
  #pragma unroll
  for (int c = 0; c < CIN_; ++c) {
    #pragma unroll
    for (int i = 0; i < 5; ++i) {
      int ih = oh * 2 + i - 2;
      bool okh = ((unsigned)ih < (unsigned)HW_);
      #pragma unroll
      for (int j = 0; j < 5; ++j) {
        int iw = ow * 2 + j - 2;
        bool ok = okh && ((unsigned)iw < (unsigned)HW_);
        float v = 0.0f;
        if (ok) v = xb[(c * HW_ + ih) * HW_ + iw];
        pre[c * 25 + i * 5 + j] = v;
      }
    }
  }
  pre[KK_] = 0.0f;

  // main loop over output channels: out dot + tot dot + running top-2
  float v1 = -3.0e38f, v2 = -3.0e38f;
  int o1 = 0, o2 = 0;
  float* outp = out + (size_t)(b * COUT_) * L_ + l;
  for (int o = 0; o < COUT_; ++o) {
    const float4* w4  = (const float4*)(Ws  + o * KP_);
    const float4* wp4 = (const float4*)(Wps + o * KP_);
    float a0 = 0.f, a1 = 0.f, t0 = 0.f, t1 = 0.f;
    #pragma unroll
    for (int kk = 0; kk < KP_ / 4; ++kk) {
      float4 wv  = w4[kk];
      float4 wpv = wp4[kk];
      a0 += wv.x  * pre[kk*4+0];
      a1 += wv.y  * pre[kk*4+1];
      a0 += wv.z  * pre[kk*4+2];
      a1 += wv.w  * pre[kk*4+3];
      t0 += wpv.x * pre[kk*4+0];
      t1 += wpv.y * pre[kk*4+1];
      t0 += wpv.z * pre[kk*4+2];
      t1 += wpv.w * pre[kk*4+3];
    }
    float ao = a0 + a1;
    float at = t0 + t1;
    outp[(size_t)o * L_] = ao;
    // strict > keeps the lower channel index on ties (matches lax.top_k)
    if (at > v1)      { v2 = v1; o2 = o1; v1 = at; o1 = o; }
    else if (at > v2) { v2 = at; o2 = o; }
  }

  // phase 2: block-local yx/yy accumulation (reuse Wps as accumulator)
  __syncthreads();                 // everyone done reading Ws/Wps
  float* yxloc = Wps;
  for (int i = tid; i < COUT_ * KP_; i += 256) yxloc[i] = 0.0f;
  for (int i = tid; i < COUT_;      i += 256) yyloc[i] = 0.0f;
  __syncthreads();

  atomicAdd(&yyloc[o1], v1);
  atomicAdd(&yyloc[o2], DELTA_ * v2);
  float* r1 = yxloc + o1 * KP_;
  float* r2 = yxloc + o2 * KP_;
  #pragma unroll
  for (int k = 0; k < KK_; ++k) {
    atomicAdd(&r1[k], pre[k]);
    atomicAdd(&r2[k], DELTA_ * pre[k]);
  }
  __syncthreads();

  // write deterministic per-block partial row: 7200 yx + 96 yy
  float* prow = part + (size_t)(b * NCHUNK + blockIdx.x) * ROW;
  for (int i = tid; i < COUT_ * KK_; i += 256) {
    int o = i / KK_, k = i - o * KK_;
    prow[i] = yxloc[o * KP_ + k];
  }
  for (int i = tid; i < COUT_; i += 256) prow[COUT_ * KK_ + i] = yyloc[i];
}

// Kernel 2: reduce 576 partial rows -> finals[7296]
__global__ __launch_bounds__(256) void k3_reduce(
    const float* __restrict__ part, float* __restrict__ finals)
{
  int i = blockIdx.x * 256 + threadIdx.x;
  if (i >= ROW) return;
  float s = 0.0f;
  for (int p = 0; p < NPART; ++p) s += part[(size_t)p * ROW + i];
  finals[i] = s;
}

// Kernel 3: ds = yx_sum - yy_sum*W; nc = max|ds|; new_W = W + LR*ds/nc.
// (the reference's 1/L cancels inside ds/nc; PREC clamp is immaterial at this scale)
__global__ __launch_bounds__(256) void k4_finalize(
    const float* __restrict__ w, const float* __restrict__ finals,
    float* __restrict__ outw)
{
  __shared__ float dsS[COUT_ * KK_];
  __shared__ float wmax[4];
  __shared__ float ncS;
  const int tid = threadIdx.x;
  float m = 0.0f;
  for (int i = tid; i < COUT_ * KK_; i += 256) {
    int o = i / KK_;
    float d = finals[i] - finals[COUT_ * KK_ + o] * w[i];
    dsS[i] = d;
    m = fmaxf(m, fabsf(d));
  }
  #pragma unroll
  for (int s = 32; s > 0; s >>= 1) m = fmaxf(m, __shfl_xor(m, s, 64));
  if ((tid & 63) == 0) wmax[tid >> 6] = m;
  __syncthreads();
  if (tid == 0) {
    float n = fmaxf(fmaxf(wmax[0], wmax[1]), fmaxf(wmax[2], wmax[3]));
    ncS = fmaxf(n, 1e-30f);
  }
  __syncthreads();
  const float scale = LR_ / ncS;
  for (int i = tid; i < COUT_ * KK_; i += 256) {
    outw[i] = w[i] + scale * dsS[i];
  }
}

extern "C" void kernel_launch(void* const* d_in, const int* in_sizes, int n_in,
                              void* d_out, int out_size, void* d_ws, size_t ws_size,
                              hipStream_t stream) {
  (void)in_sizes; (void)n_in; (void)out_size; (void)ws_size;
  const float* x = (const float*)d_in[0];   // [64,3,96,96]
  const float* w = (const float*)d_in[1];   // [96,3,5,5]
  float* out  = (float*)d_out;              // conv out [64,96,48,48]
  float* outw = out + OUT_ELEMS;            // new_weight [96,75]
  float* part   = (float*)d_ws;                      // [576][7296]
  float* finals = part + (size_t)NPART * ROW;        // [7296]

  k1_main   <<<dim3(NCHUNK, B_), 256, 0, stream>>>(x, w, out, part);
  k3_reduce <<<dim3((ROW + 255) / 256), 256, 0, stream>>>(part, finals);
  k4_finalize<<<dim3(1), 256, 0, stream>>>(w, finals, outw);
}

// Round 2
// 298.826 us; speedup vs baseline: 1.0873x; 1.0873x over previous
//
#include <hip/hip_runtime.h>

// Problem constants
#define B_     64
#define HW_    96
#define COUT_  96
#define KK_    75          // CIN*KH*KW
#define KP_    76          // padded K (multiple of 4 for float4 reads)
#define HOUT_  48
#define L_     2304        // 48*48
#define LR_    0.02f
#define DELTA_ -0.4f
#define OUT_ELEMS (B_*COUT_*L_)
#define NCHUNK2 9              // k2 l-chunks per batch (2304/256)
#define NPART  (B_*NCHUNK2)    // 576 partial rows
#define ROW    (COUT_*KK_ + COUT_)   // 7296 floats: 7200 yx + 96 yy

__device__ __forceinline__ void im2col_load(const float* __restrict__ xb, int l,
                                            float* __restrict__ pre) {
  const int oh = l / HOUT_, ow = l - oh * HOUT_;
  #pragma unroll
  for (int c = 0; c < 3; ++c) {
    #pragma unroll
    for (int i = 0; i < 5; ++i) {
      int ih = oh * 2 + i - 2;
      bool okh = ((unsigned)ih < (unsigned)HW_);
      #pragma unroll
      for (int j = 0; j < 5; ++j) {
        int iw = ow * 2 + j - 2;
        float v = 0.0f;
        if (okh && ((unsigned)iw < (unsigned)HW_)) v = xb[(c * HW_ + ih) * HW_ + iw];
        pre[c * 25 + i * 5 + j] = v;
      }
    }
  }
  pre[KK_] = 0.0f;
}

// Kernel 1: conv forward + tot + per-position top-2.
// grid (36, 64), block 256 = 4 waves; wave q handles channels [24q, 24q+24)
// for 64 consecutive positions. Wp = w*|w| computed on the fly (abs modifier
// is free on the mul source), so only one 29.2KB weight buffer in LDS.
__global__ __launch_bounds__(256, 4) void k1_conv(
    const float* __restrict__ x, const float* __restrict__ w,
    float* __restrict__ out, float4* __restrict__ top2)
{
  __shared__ __align__(16) float Ws[COUT_ * KP_];
  __shared__ float4 mrg[4][64];
  const int tid = threadIdx.x;
  for (int idx = tid; idx < COUT_ * KP_; idx += 256) {
    int o = idx / KP_, k = idx - o * KP_;
    Ws[idx] = (k < KK_) ? w[o * KK_ + k] : 0.0f;
  }
  __syncthreads();

  const int p = tid & 63, q = tid >> 6;
  const int b = blockIdx.y;
  const int l = blockIdx.x * 64 + p;
  float pre[KP_];
  im2col_load(x + (size_t)b * (3 * HW_ * HW_), l, pre);

  float v1 = -3.0e38f, v2 = -3.0e38f;
  int o1 = 0, o2 = 0;
  float* outp = out + (size_t)b * COUT_ * L_ + l;
  #pragma unroll 1
  for (int oo = 0; oo < COUT_ / 4; ++oo) {
    const int o = q * (COUT_ / 4) + oo;
    const float4* w4 = (const float4*)(Ws + o * KP_);
    float a0 = 0.f, a1 = 0.f, t0 = 0.f, t1 = 0.f;
    #pragma unroll
    for (int kk = 0; kk < KP_ / 4; ++kk) {
      float4 wv = w4[kk];
      a0 = fmaf(wv.x, pre[kk*4+0], a0);
      t0 = fmaf(wv.x * fabsf(wv.x), pre[kk*4+0], t0);
      a1 = fmaf(wv.y, pre[kk*4+1], a1);
      t1 = fmaf(wv.y * fabsf(wv.y), pre[kk*4+1], t1);
      a0 = fmaf(wv.z, pre[kk*4+2], a0);
      t0 = fmaf(wv.z * fabsf(wv.z), pre[kk*4+2], t0);
      a1 = fmaf(wv.w, pre[kk*4+3], a1);
      t1 = fmaf(wv.w * fabsf(wv.w), pre[kk*4+3], t1);
    }
    outp[(size_t)o * L_] = a0 + a1;
    float at = t0 + t1;
    if (at > v1)      { v2 = v1; o2 = o1; v1 = at; o1 = o; }
    else if (at > v2) { v2 = at; o2 = o; }
  }
  mrg[q][p] = make_float4(v1, __int_as_float(o1), v2, __int_as_float(o2));
  __syncthreads();

  if (q == 0) {   // wave 0 merges the four per-quarter top-2 lists
    float V1 = -3.0e38f, V2 = -3.0e38f;
    int O1 = 0, O2 = 0;
    #pragma unroll
    for (int qq = 0; qq < 4; ++qq) {
      float4 m = mrg[qq][p];
      float cv = m.x; int co = __float_as_int(m.y);
      if (cv > V1)      { V2 = V1; O2 = O1; V1 = cv; O1 = co; }
      else if (cv > V2) { V2 = cv; O2 = co; }
      cv = m.z; co = __float_as_int(m.w);
      if (cv > V1)      { V2 = V1; O2 = O1; V1 = cv; O1 = co; }
      else if (cv > V2) { V2 = cv; O2 = co; }
    }
    top2[(size_t)b * L_ + l] =
        make_float4(V1, __int_as_float(O1), V2, __int_as_float(O2));
  }
}

// Kernel 2: sparse Hebbian scatter. grid (9,64), block 256 (one thread per
// position). Re-does the cheap im2col (x is L1/L2-resident), accumulates
// yx/yy into LDS, writes one deterministic partial row per block.
__global__ __launch_bounds__(256) void k2_scatter(
    const float* __restrict__ x, const float4* __restrict__ top2,
    float* __restrict__ part)
{
  __shared__ float yx[COUT_ * KP_];
  __shared__ float yy[COUT_];
  const int tid = threadIdx.x;
  for (int i = tid; i < COUT_ * KP_; i += 256) yx[i] = 0.0f;
  for (int i = tid; i < COUT_;      i += 256) yy[i] = 0.0f;
  __syncthreads();

  const int b = blockIdx.y;
  const int l = blockIdx.x * 256 + tid;
  float pre[KP_];
  im2col_load(x + (size_t)b * (3 * HW_ * HW_), l, pre);
  float4 t2 = top2[(size_t)b * L_ + l];
  const int o1 = __float_as_int(t2.y), o2 = __float_as_int(t2.w);
  atomicAdd(&yy[o1], t2.x);
  atomicAdd(&yy[o2], DELTA_ * t2.z);
  float* r1 = yx + o1 * KP_;
  float* r2 = yx + o2 * KP_;
  #pragma unroll
  for (int k = 0; k < KK_; ++k) {
    atomicAdd(&r1[k], pre[k]);
    atomicAdd(&r2[k], DELTA_ * pre[k]);
  }
  __syncthreads();

  float* prow = part + (size_t)(b * NCHUNK2 + blockIdx.x) * ROW;
  for (int i = tid; i < COUT_ * KK_; i += 256) {
    int o = i / KK_, k = i - o * KK_;
    prow[i] = yx[o * KP_ + k];
  }
  for (int i = tid; i < COUT_; i += 256) prow[COUT_ * KK_ + i] = yy[i];
}

// Kernel 3: reduce 576 partial rows -> finals[7296]
__global__ __launch_bounds__(256) void k3_reduce(
    const float* __restrict__ part, float* __restrict__ finals)
{
  int i = blockIdx.x * 256 + threadIdx.x;
  if (i >= ROW) return;
  float s = 0.0f;
  for (int p = 0; p < NPART; ++p) s += part[(size_t)p * ROW + i];
  finals[i] = s;
}

// Kernel 4: ds = yx - yy*W; nc = max|ds|; new_W = W + LR*ds/nc.
// (the reference's 1/L cancels inside ds/nc)
__global__ __launch_bounds__(256) void k4_finalize(
    const float* __restrict__ w, const float* __restrict__ finals,
    float* __restrict__ outw)
{
  __shared__ float dsS[COUT_ * KK_];
  __shared__ float wmax[4];
  __shared__ float ncS;
  const int tid = threadIdx.x;
  float m = 0.0f;
  for (int i = tid; i < COUT_ * KK_; i += 256) {
    int o = i / KK_;
    float d = finals[i] - finals[COUT_ * KK_ + o] * w[i];
    dsS[i] = d;
    m = fmaxf(m, fabsf(d));
  }
  #pragma unroll
  for (int s = 32; s > 0; s >>= 1) m = fmaxf(m, __shfl_xor(m, s, 64));
  if ((tid & 63) == 0) wmax[tid >> 6] = m;
  __syncthreads();
  if (tid == 0) {
    float n = fmaxf(fmaxf(wmax[0], wmax[1]), fmaxf(wmax[2], wmax[3]));
    ncS = fmaxf(n, 1e-30f);
  }
  __syncthreads();
  const float scale = LR_ / ncS;
  for (int i = tid; i < COUT_ * KK_; i += 256) {
    outw[i] = w[i] + scale * dsS[i];
  }
}

extern "C" void kernel_launch(void* const* d_in, const int* in_sizes, int n_in,
                              void* d_out, int out_size, void* d_ws, size_t ws_size,
                              hipStream_t stream) {
  (void)in_sizes; (void)n_in; (void)out_size; (void)ws_size;
  const float* x = (const float*)d_in[0];   // [64,3,96,96]
  const float* w = (const float*)d_in[1];   // [96,3,5,5]
  float* out  = (float*)d_out;              // conv out [64,96,48,48]
  float* outw = out + OUT_ELEMS;            // new_weight [96,75]

  float4* top2  = (float4*)d_ws;                       // [64*2304] tuples
  float*  part  = (float*)d_ws + (size_t)4 * B_ * L_;  // [576][7296]
  float*  finals = part + (size_t)NPART * ROW;         // [7296]

  k1_conv   <<<dim3(L_ / 64, B_), 256, 0, stream>>>(x, w, out, top2);
  k2_scatter<<<dim3(NCHUNK2, B_), 256, 0, stream>>>(x, top2, part);
  k3_reduce <<<dim3((ROW + 255) / 256), 256, 0, stream>>>(part, finals);
  k4_finalize<<<dim3(1), 256, 0, stream>>>(w, finals, outw);
}